// Round 5
// baseline (52.144 us; speedup 1.0000x reference)
//
#include <hip/hip_runtime.h>
#include <hip/hip_cooperative_groups.h>
#include <float.h>
#include <math.h>

namespace cg = cooperative_groups;

#define NB 32
#define LD 512
#define LP 4096
#define HD 128
#define PV 26
// ws layout (float index):
//   ws_m    [NB*8]       @ 0
//   ws_den  [NB*8]       @ 256
//   ws_col  [NB*8*32]    @ 512
//   ws_part [NB*8*128]   @ 8704
//   ws_hist [NB*8*32]int @ 41472

__global__ __launch_bounds__(512)
void k_fused(const int* __restrict__ drug_ids, const int* __restrict__ prot_ids,
             const float* __restrict__ drug_emb, const float* __restrict__ prot_emb,
             const float* __restrict__ W1, const float* __restrict__ b1,
             const float* __restrict__ W2, const float* __restrict__ b2,
             float* __restrict__ out, float* __restrict__ wsf) {
    float* ws_m    = wsf;
    float* ws_den  = wsf + 256;
    float* ws_col  = wsf + 512;
    float* ws_part = wsf + 8704;
    int*   ws_hist = (int*)(wsf + 41472);

    int t = threadIdx.x;
    int wid = t >> 6, lane = t & 63;

    __shared__ float red[8][64][27];   // 55.3 KB
    __shared__ float ev[64];
    __shared__ unsigned wor[8];
    __shared__ int hist[32];

    // ---------------- Phase A: per (batch, chunk) ----------------
    {
        int b = blockIdx.x >> 3, chunk = blockIdx.x & 7;
        int q = __builtin_amdgcn_readfirstlane(wid);
        int l = chunk * 64 + lane;

        if (t < 32) hist[t] = 0;

        // presence mask over all 4096 ids (8/thread)
        const int4* pid4 = reinterpret_cast<const int4*>(prot_ids + b * LP);
        int4 i0 = pid4[t], i1 = pid4[t + 512];
        unsigned pm = (1u << i0.x) | (1u << i0.y) | (1u << i0.z) | (1u << i0.w)
                    | (1u << i1.x) | (1u << i1.y) | (1u << i1.z) | (1u << i1.w);
        #pragma unroll
        for (int off = 32; off; off >>= 1) pm |= __shfl_xor(pm, off, 64);
        if (lane == 0) wor[q] = pm;

        // A sixteenth-row preload (16 k-floats, kept for d_vec partial too)
        const float* __restrict__ A =
            drug_emb + (size_t)drug_ids[b * LD + l] * HD + q * 16;
        float4 a[4];
        #pragma unroll
        for (int i = 0; i < 4; ++i) a[i] = reinterpret_cast<const float4*>(A)[i];

        __syncthreads();   // hist zeroed

        // own-slice histogram (512 ids, 1/thread)
        atomicAdd(&hist[prot_ids[b * LP + chunk * 512 + t]], 1);

        const float* __restrict__ Bq = prot_emb + q * 16;
        float s[PV];
        #pragma unroll
        for (int v = 0; v < PV; ++v) s[v] = 0.f;
        #pragma unroll
        for (int i = 0; i < 4; ++i) {
            float4 av = a[i];
            #pragma unroll
            for (int v = 0; v < PV; ++v) {
                float4 p = reinterpret_cast<const float4*>(Bq + v * HD)[i];
                s[v] = fmaf(av.x, p.x, fmaf(av.y, p.y,
                       fmaf(av.z, p.z, fmaf(av.w, p.w, s[v]))));
            }
        }
        #pragma unroll
        for (int v = 0; v < PV; ++v) red[q][lane][v] = s[v];
        __syncthreads();

        unsigned msk = wor[0] | wor[1] | wor[2] | wor[3]
                     | wor[4] | wor[5] | wor[6] | wor[7];

        // K-reduce 8 slices
        for (int o = t; o < 64 * PV; o += 512) {
            int l2 = o / PV, v = o - l2 * PV;
            red[0][l2][v] = red[0][l2][v] + red[1][l2][v] + red[2][l2][v]
                          + red[3][l2][v] + red[4][l2][v] + red[5][l2][v]
                          + red[6][l2][v] + red[7][l2][v];
        }
        __syncthreads();

        if (wid == 0) {
            // masked row-max, chunk max, local softmax numerators + denom
            float r = -FLT_MAX;
            #pragma unroll
            for (int v = 0; v < PV; ++v)
                if ((msk >> v) & 1) r = fmaxf(r, red[0][lane][v]);
            float m = r;
            #pragma unroll
            for (int off = 32; off; off >>= 1) m = fmaxf(m, __shfl_xor(m, off, 64));
            float e = __expf(r - m);
            ev[lane] = e;
            float den = e;
            #pragma unroll
            for (int off = 32; off; off >>= 1) den += __shfl_xor(den, off, 64);
            if (lane == 0) {
                ws_m[(b << 3) + chunk] = m;
                ws_den[(b << 3) + chunk] = den;
            }
        } else if (wid == 1 && lane < PV) {
            float cmx = -FLT_MAX;
            for (int r = 0; r < 64; ++r) cmx = fmaxf(cmx, red[0][r][lane]);
            ws_col[((b << 3) + chunk) * 32 + lane] = cmx;
        }
        __syncthreads();

        // d_vec partial: red[q][lane][c] = e_lane * a_c  (h = q*16+c)
        float myE = ev[lane];
        #pragma unroll
        for (int i = 0; i < 4; ++i) {
            red[q][lane][4 * i + 0] = myE * a[i].x;
            red[q][lane][4 * i + 1] = myE * a[i].y;
            red[q][lane][4 * i + 2] = myE * a[i].z;
            red[q][lane][4 * i + 3] = myE * a[i].w;
        }
        __syncthreads();

        if (t < 128) {
            int qq = t >> 4, c = t & 15;
            float sum = 0.f;
            for (int r = 0; r < 64; ++r) sum += red[qq][r][c];
            ws_part[((b << 3) + chunk) * 128 + qq * 16 + c] = sum;
        }
        if (t < 32) ws_hist[((b << 3) + chunk) * 32 + t] = hist[t];
    }

    cg::this_grid().sync();

    // ---------------- Phase B: one block per batch ----------------
    if (blockIdx.x >= NB) return;
    int b = blockIdx.x;

    __shared__ float sscale[8], ew[32], comb[2 * HD], hpart[4][64];
    __shared__ float sInvD, sInvP;

    if (t < 8) {
        float m = ws_m[(b << 3) + t];
        float M = m;
        #pragma unroll
        for (int off = 4; off; off >>= 1) M = fmaxf(M, __shfl_xor(M, off, 8));
        float sc = __expf(m - M);
        float dd = sc * ws_den[(b << 3) + t];
        float D = dd;
        #pragma unroll
        for (int off = 4; off; off >>= 1) D += __shfl_xor(D, off, 8);
        sscale[t] = sc;
        if (t == 0) sInvD = 1.f / D;
    } else if (wid == 1) {
        int v = lane;
        float cmx = -FLT_MAX; int c = 0;
        if (v < PV) {
            #pragma unroll
            for (int c8 = 0; c8 < 8; ++c8) {
                cmx = fmaxf(cmx, ws_col[((b << 3) + c8) * 32 + v]);
                c += ws_hist[((b << 3) + c8) * 32 + v];
            }
        }
        float m0 = (c > 0) ? cmx : -FLT_MAX;
        float M2 = m0;
        #pragma unroll
        for (int off = 32; off; off >>= 1) M2 = fmaxf(M2, __shfl_xor(M2, off, 64));
        float w = (c > 0) ? (float)c * __expf(cmx - M2) : 0.f;
        float S = w;
        #pragma unroll
        for (int off = 32; off; off >>= 1) S += __shfl_xor(S, off, 64);
        if (v < 32) ew[v] = (v < PV) ? w : 0.f;
        if (lane == 0) sInvP = 1.f / S;
    }
    __syncthreads();

    if (t < HD) {
        float d = 0.f;
        #pragma unroll
        for (int c8 = 0; c8 < 8; ++c8)
            d = fmaf(sscale[c8], ws_part[((b << 3) + c8) * 128 + t], d);
        comb[t] = d * sInvD;
    } else if (t < 2 * HD) {
        int h = t - HD;
        float p = 0.f;
        #pragma unroll
        for (int v = 0; v < PV; ++v)
            p = fmaf(ew[v], prot_emb[v * HD + h], p);
        comb[t] = p * sInvP;
    }
    __syncthreads();

    if (t < 256) {
        int j = t & 63, seg = t >> 6;
        float acc = 0.f;
        #pragma unroll
        for (int k = 0; k < 64; ++k) {
            int kk = seg * 64 + k;
            acc = fmaf(comb[kk], W1[kk * 64 + j], acc);
        }
        hpart[seg][j] = acc;
    }
    __syncthreads();
    if (t < 64) {
        float hj = b1[t] + hpart[0][t] + hpart[1][t] + hpart[2][t] + hpart[3][t];
        hj = fmaxf(hj, 0.f);
        float o = hj * W2[t];
        #pragma unroll
        for (int off = 32; off; off >>= 1) o += __shfl_xor(o, off, 64);
        if (t == 0) out[b] = o + b2[0];
    }
}

extern "C" void kernel_launch(void* const* d_in, const int* in_sizes, int n_in,
                              void* d_out, int out_size, void* d_ws, size_t ws_size,
                              hipStream_t stream) {
    const int*   drug_ids = (const int*)d_in[0];
    const int*   prot_ids = (const int*)d_in[1];
    const float* drug_emb = (const float*)d_in[2];
    const float* prot_emb = (const float*)d_in[3];
    const float* W1 = (const float*)d_in[4];
    const float* b1 = (const float*)d_in[5];
    const float* W2 = (const float*)d_in[6];
    const float* b2 = (const float*)d_in[7];
    float* out = (float*)d_out;
    float* wsf = (float*)d_ws;

    void* kargs[] = { (void*)&drug_ids, (void*)&prot_ids, (void*)&drug_emb,
                      (void*)&prot_emb, (void*)&W1, (void*)&b1, (void*)&W2,
                      (void*)&b2, (void*)&out, (void*)&wsf };
    hipLaunchCooperativeKernel((void*)k_fused, dim3(NB * 8), dim3(512),
                               kargs, 0, stream);
}

// Round 6
// 17.163 us; speedup vs baseline: 3.0381x; 3.0381x over previous
//
#include <hip/hip_runtime.h>
#include <float.h>
#include <math.h>

#define NB 32
#define LD 512
#define LP 4096
#define HD 128
#define PV 26
// ws layout (float index):
//   ws_m    [NB*8]       @ 0
//   ws_den  [NB*8]       @ 256
//   ws_col  [NB*8*32]    @ 512
//   ws_part [NB*8*128]   @ 8704
//   ws_hist [NB*8*32]int @ 41472

// K1: per (batch, 64-row chunk): scores, masked row-softmax locals (m, den),
// per-chunk colmax, per-chunk histogram, and d_vec partial from A registers.
__global__ __launch_bounds__(512)
void k_part(const int* __restrict__ drug_ids, const int* __restrict__ prot_ids,
            const float* __restrict__ drug_emb, const float* __restrict__ prot_emb,
            float* __restrict__ wsf) {
    float* ws_m    = wsf;
    float* ws_den  = wsf + 256;
    float* ws_col  = wsf + 512;
    float* ws_part = wsf + 8704;
    int*   ws_hist = (int*)(wsf + 41472);

    int t = threadIdx.x;
    int wid = t >> 6, lane = t & 63;
    int b = blockIdx.x >> 3, chunk = blockIdx.x & 7;
    int q = __builtin_amdgcn_readfirstlane(wid);
    int l = chunk * 64 + lane;

    __shared__ float red[8][64][27];   // 55.3 KB
    __shared__ float ev[64];
    __shared__ unsigned wor[8];
    __shared__ int hist[32];

    if (t < 32) hist[t] = 0;

    // presence mask over all 4096 ids (8/thread)
    const int4* pid4 = reinterpret_cast<const int4*>(prot_ids + b * LP);
    int4 i0 = pid4[t], i1 = pid4[t + 512];
    unsigned pm = (1u << i0.x) | (1u << i0.y) | (1u << i0.z) | (1u << i0.w)
                | (1u << i1.x) | (1u << i1.y) | (1u << i1.z) | (1u << i1.w);
    #pragma unroll
    for (int off = 32; off; off >>= 1) pm |= __shfl_xor(pm, off, 64);
    if (lane == 0) wor[q] = pm;

    // A sixteenth-row preload (16 k-floats; reused for d_vec partial)
    const float* __restrict__ A =
        drug_emb + (size_t)drug_ids[b * LD + l] * HD + q * 16;
    float4 a[4];
    #pragma unroll
    for (int i = 0; i < 4; ++i) a[i] = reinterpret_cast<const float4*>(A)[i];

    __syncthreads();   // hist zeroed

    // own-slice histogram (512 ids, 1/thread)
    atomicAdd(&hist[prot_ids[b * LP + chunk * 512 + t]], 1);

    const float* __restrict__ Bq = prot_emb + q * 16;
    float s[PV];
    #pragma unroll
    for (int v = 0; v < PV; ++v) s[v] = 0.f;
    #pragma unroll
    for (int i = 0; i < 4; ++i) {
        float4 av = a[i];
        #pragma unroll
        for (int v = 0; v < PV; ++v) {
            float4 p = reinterpret_cast<const float4*>(Bq + v * HD)[i];
            s[v] = fmaf(av.x, p.x, fmaf(av.y, p.y,
                   fmaf(av.z, p.z, fmaf(av.w, p.w, s[v]))));
        }
    }
    #pragma unroll
    for (int v = 0; v < PV; ++v) red[q][lane][v] = s[v];
    __syncthreads();

    unsigned msk = wor[0] | wor[1] | wor[2] | wor[3]
                 | wor[4] | wor[5] | wor[6] | wor[7];

    // K-reduce 8 slices
    for (int o = t; o < 64 * PV; o += 512) {
        int l2 = o / PV, v = o - l2 * PV;
        red[0][l2][v] = red[0][l2][v] + red[1][l2][v] + red[2][l2][v]
                      + red[3][l2][v] + red[4][l2][v] + red[5][l2][v]
                      + red[6][l2][v] + red[7][l2][v];
    }
    __syncthreads();

    if (wid == 0) {
        float r = -FLT_MAX;
        #pragma unroll
        for (int v = 0; v < PV; ++v)
            if ((msk >> v) & 1) r = fmaxf(r, red[0][lane][v]);
        float m = r;
        #pragma unroll
        for (int off = 32; off; off >>= 1) m = fmaxf(m, __shfl_xor(m, off, 64));
        float e = __expf(r - m);
        ev[lane] = e;
        float den = e;
        #pragma unroll
        for (int off = 32; off; off >>= 1) den += __shfl_xor(den, off, 64);
        if (lane == 0) {
            ws_m[(b << 3) + chunk] = m;
            ws_den[(b << 3) + chunk] = den;
        }
    } else if (wid == 1 && lane < PV) {
        float cmx = -FLT_MAX;
        for (int r = 0; r < 64; ++r) cmx = fmaxf(cmx, red[0][r][lane]);
        ws_col[((b << 3) + chunk) * 32 + lane] = cmx;
    }
    __syncthreads();

    // d_vec partial: red[q][lane][c] = e_lane * a_c  (h = q*16+c)
    float myE = ev[lane];
    #pragma unroll
    for (int i = 0; i < 4; ++i) {
        red[q][lane][4 * i + 0] = myE * a[i].x;
        red[q][lane][4 * i + 1] = myE * a[i].y;
        red[q][lane][4 * i + 2] = myE * a[i].z;
        red[q][lane][4 * i + 3] = myE * a[i].w;
    }
    __syncthreads();

    if (t < 128) {
        int qq = t >> 4, c = t & 15;
        float sum = 0.f;
        for (int r = 0; r < 64; ++r) sum += red[qq][r][c];
        ws_part[((b << 3) + chunk) * 128 + qq * 16 + c] = sum;
    }
    if (t < 32) ws_hist[((b << 3) + chunk) * 32 + t] = hist[t];
}

// K2: chunk merge (flash rescale), protein softmax, p_vec, MLP.
// 32 blocks x 256 threads.
__global__ __launch_bounds__(256)
void k_final(const float* __restrict__ prot_emb,
             const float* __restrict__ W1, const float* __restrict__ b1,
             const float* __restrict__ W2, const float* __restrict__ b2,
             float* __restrict__ out, const float* __restrict__ wsf) {
    const float* ws_m    = wsf;
    const float* ws_den  = wsf + 256;
    const float* ws_col  = wsf + 512;
    const float* ws_part = wsf + 8704;
    const int*   ws_hist = (const int*)(wsf + 41472);

    int b = blockIdx.x;
    int t = threadIdx.x;
    int wid = t >> 6, lane = t & 63;

    __shared__ float sscale[8], ew[32], comb[2 * HD], hpart[4][64];
    __shared__ float sInvD, sInvP;

    if (t < 8) {
        float m = ws_m[(b << 3) + t];
        float M = m;
        #pragma unroll
        for (int off = 4; off; off >>= 1) M = fmaxf(M, __shfl_xor(M, off, 8));
        float sc = __expf(m - M);
        float dd = sc * ws_den[(b << 3) + t];
        float D = dd;
        #pragma unroll
        for (int off = 4; off; off >>= 1) D += __shfl_xor(D, off, 8);
        sscale[t] = sc;
        if (t == 0) sInvD = 1.f / D;
    } else if (wid == 1) {
        int v = lane;
        float cmx = -FLT_MAX; int c = 0;
        if (v < PV) {
            #pragma unroll
            for (int c8 = 0; c8 < 8; ++c8) {
                cmx = fmaxf(cmx, ws_col[((b << 3) + c8) * 32 + v]);
                c += ws_hist[((b << 3) + c8) * 32 + v];
            }
        }
        float m0 = (c > 0) ? cmx : -FLT_MAX;
        float M2 = m0;
        #pragma unroll
        for (int off = 32; off; off >>= 1) M2 = fmaxf(M2, __shfl_xor(M2, off, 64));
        float w = (c > 0) ? (float)c * __expf(cmx - M2) : 0.f;
        float S = w;
        #pragma unroll
        for (int off = 32; off; off >>= 1) S += __shfl_xor(S, off, 64);
        if (v < 32) ew[v] = (v < PV) ? w : 0.f;
        if (lane == 0) sInvP = 1.f / S;
    }
    __syncthreads();

    if (t < HD) {
        float d = 0.f;
        #pragma unroll
        for (int c8 = 0; c8 < 8; ++c8)
            d = fmaf(sscale[c8], ws_part[((b << 3) + c8) * 128 + t], d);
        comb[t] = d * sInvD;
    } else {
        int h = t - HD;
        float p = 0.f;
        #pragma unroll
        for (int v = 0; v < PV; ++v)
            p = fmaf(ew[v], prot_emb[v * HD + h], p);
        comb[t] = p * sInvP;
    }
    __syncthreads();

    // MLP 256->64 (4-way K split) -> relu -> 64->1
    {
        int j = t & 63, seg = t >> 6;
        float acc = 0.f;
        #pragma unroll
        for (int k = 0; k < 64; ++k) {
            int kk = seg * 64 + k;
            acc = fmaf(comb[kk], W1[kk * 64 + j], acc);
        }
        hpart[seg][j] = acc;
    }
    __syncthreads();
    if (t < 64) {
        float hj = b1[t] + hpart[0][t] + hpart[1][t] + hpart[2][t] + hpart[3][t];
        hj = fmaxf(hj, 0.f);
        float o = hj * W2[t];
        #pragma unroll
        for (int off = 32; off; off >>= 1) o += __shfl_xor(o, off, 64);
        if (t == 0) out[b] = o + b2[0];
    }
}

extern "C" void kernel_launch(void* const* d_in, const int* in_sizes, int n_in,
                              void* d_out, int out_size, void* d_ws, size_t ws_size,
                              hipStream_t stream) {
    const int*   drug_ids = (const int*)d_in[0];
    const int*   prot_ids = (const int*)d_in[1];
    const float* drug_emb = (const float*)d_in[2];
    const float* prot_emb = (const float*)d_in[3];
    const float* W1 = (const float*)d_in[4];
    const float* b1 = (const float*)d_in[5];
    const float* W2 = (const float*)d_in[6];
    const float* b2 = (const float*)d_in[7];
    float* out = (float*)d_out;
    float* wsf = (float*)d_ws;

    k_part<<<NB * 8, 512, 0, stream>>>(drug_ids, prot_ids, drug_emb, prot_emb, wsf);
    k_final<<<NB, 256, 0, stream>>>(prot_emb, W1, b1, W2, b2, out, wsf);
}